// Round 2
// baseline (363.455 us; speedup 1.0000x reference)
//
#include <hip/hip_runtime.h>

// Problem constants
#define B_   32
#define H_   64
#define W_   64
#define CIN  128
#define F_   256
#define K_   1152          // 3*3*128
#define M_   4096          // H*W per batch

#define WBT_BYTES ((size_t)B_ * F_ * K_ * 2)   // 18,874,368
#define ZPAGE_OFF WBT_BYTES                    // 256B zero page after WbT

typedef __attribute__((ext_vector_type(8))) short bf16x8;
typedef __attribute__((ext_vector_type(4))) float f32x4;

__device__ __forceinline__ unsigned short f2bf(float x) {
    unsigned int u = __builtin_bit_cast(unsigned int, x);
    u = u + 0x7fffu + ((u >> 16) & 1u);   // RNE
    return (unsigned short)(u >> 16);
}

// pack two floats -> two bf16 (round-to-nearest, ties away) in one v_perm
__device__ __forceinline__ unsigned pkbf(float a, float b) {
    unsigned ua = __builtin_bit_cast(unsigned, a) + 0x8000u;
    unsigned ub = __builtin_bit_cast(unsigned, b) + 0x8000u;
    // result bytes: [ua.b2, ua.b3, ub.b2, ub.b3]
    return __builtin_amdgcn_perm(ub, ua, 0x07060302u);
}

__device__ __forceinline__ bf16x8 cvt8(f32x4 lo, f32x4 hi) {
    union { unsigned u[4]; bf16x8 v; } o;
    o.u[0] = pkbf(lo[0], lo[1]);
    o.u[1] = pkbf(lo[2], lo[3]);
    o.u[2] = pkbf(hi[0], hi[1]);
    o.u[3] = pkbf(hi[2], hi[3]);
    return o.v;
}

__device__ __forceinline__ void async16(const void* g, void* l) {
    __builtin_amdgcn_global_load_lds(
        (const __attribute__((address_space(1))) unsigned int*)g,
        (__attribute__((address_space(3))) unsigned int*)l, 16, 0, 0);
}

// ---------------------------------------------------------------------------
// Kernel B: WbT[b][f][k] = bf16( W[k][f] * Werr[b][k][f] )  + zero page init
// ---------------------------------------------------------------------------
__global__ void wbt_kernel(const float* __restrict__ W,
                           const float* __restrict__ Werr,
                           unsigned short* __restrict__ WbT,
                           unsigned int* __restrict__ zpage) {
    __shared__ float tile[32 * 65];
    int bid = blockIdx.x;
    int ft   = bid & 3;
    int rest = bid >> 2;
    int kt   = rest % 36;
    int b    = rest / 36;
    int k0 = kt * 32;
    int f0 = ft * 64;
    int t  = threadIdx.x;

    if (bid == 0 && t < 64) zpage[t] = 0u;   // 256B zero page, every call

    #pragma unroll
    for (int i = 0; i < 8; ++i) {
        int e = i * 256 + t;
        int kl = e >> 6;
        int fl = e & 63;
        size_t src = (size_t)(k0 + kl) * F_ + f0 + fl;
        tile[kl * 65 + fl] = W[src] * Werr[(size_t)b * (K_ * F_) + src];
    }
    __syncthreads();
    #pragma unroll
    for (int i = 0; i < 8; ++i) {
        int e = i * 256 + t;
        int kl = e & 31;
        int fl = e >> 5;
        size_t dst = ((size_t)b * F_ + f0 + fl) * K_ + k0 + kl;
        WbT[dst] = f2bf(tile[kl * 65 + fl]);
    }
}

// ---------------------------------------------------------------------------
// Kernel C: implicit-im2col GEMM, A staged fp32 directly from X (zero-page
// redirect for SAME padding, XOR-swizzled LDS units), cvt->bf16 post ds_read.
// block = 256 thr (4 waves), tile 128(M) x 128(N), BK=32, 36 K-steps.
// grid = 32 batches * 32 mtiles * 2 ntiles = 2048
// ---------------------------------------------------------------------------
__global__ __launch_bounds__(256, 2)
void gemm_kernel(const float* __restrict__ X,
                 const unsigned short* __restrict__ WbT,
                 const float* __restrict__ zpage,
                 const float* __restrict__ bias,
                 const float* __restrict__ Berr,
                 float* __restrict__ Out) {
    __shared__ float          As[128 * 32];    // fp32, 16KB, rows of 128B
    __shared__ unsigned short Bs[128 * 32];    // bf16,  8KB, rows of 64B

    int bid = blockIdx.x;
    int b   = bid >> 6;
    int r   = bid & 63;
    int mt  = r >> 1;
    int nt  = r & 1;
    int pm0 = mt * 128;

    int t    = threadIdx.x;
    int lane = t & 63;
    int wv   = t >> 6;
    int wm   = wv >> 1;
    int wn   = wv & 1;
    int l16  = lane & 15;
    int quad = lane >> 4;

    // ---- per-thread A staging state: 4 chunks of 16B ----
    const char* Abase[4];
    unsigned    vmask[4];
    int         ldsA[4];
    #pragma unroll
    for (int cc = 0; cc < 4; ++cc) {
        int c     = t + cc * 256;          // 0..1023
        int ml    = c >> 3;                // row 0..127
        int offsw = c & 7;                 // physical 16B unit in row
        int off   = offsw ^ (ml & 7);      // logical float4 index (swizzle)
        int hb    = mt * 2 + (ml >> 6);    // output h, 0..63
        int wwv   = ml & 63;               // output w
        long long o0 = (((long long)b * 64 + hb - 1) * 64 + (wwv - 1)) * 128 + off * 4;
        Abase[cc] = (const char*)X + o0 * 4;
        unsigned vm = 0;
        #pragma unroll
        for (int khw = 0; khw < 9; ++khw) {
            int kh = (khw * 11) >> 5;
            int kw = khw - kh * 3;
            bool ok = ((unsigned)(hb + kh - 1) < 64u) && ((unsigned)(wwv + kw - 1) < 64u);
            vm |= (unsigned)ok << khw;
        }
        vmask[cc] = vm;
        ldsA[cc]  = c * 4;                 // float index (16B chunk c)
    }
    // ---- per-thread B staging state: 2 chunks of 16B ----
    const unsigned short* wb = WbT + ((size_t)(b * F_ + nt * 128)) * K_;
    const unsigned short* Bbase[2];
    int ldsB[2];
    #pragma unroll
    for (int cc = 0; cc < 2; ++cc) {
        int c   = t + cc * 256;            // 0..511
        int nl  = c >> 2;
        int off = c & 3;
        Bbase[cc] = wb + (size_t)nl * K_ + off * 8;
        ldsB[cc]  = c * 8;                 // short index
    }

    f32x4 acc[4][4];
    #pragma unroll
    for (int mi = 0; mi < 4; ++mi)
        #pragma unroll
        for (int ni = 0; ni < 4; ++ni)
            acc[mi][ni] = (f32x4){0.f, 0.f, 0.f, 0.f};

    int sxor = l16 & 7;

    for (int kt = 0; kt < 36; ++kt) {
        int khw  = kt >> 2;                        // 0..8, block-uniform
        int kh   = (khw * 11) >> 5;
        int kw   = khw - kh * 3;
        int koff = (kh * 8192 + kw * 128 + ((kt & 3) << 5)) * 4;  // bytes

        #pragma unroll
        for (int cc = 0; cc < 4; ++cc) {
            const void* g = ((vmask[cc] >> khw) & 1) ? (const void*)(Abase[cc] + koff)
                                                     : (const void*)zpage;
            async16(g, &As[ldsA[cc]]);
        }
        #pragma unroll
        for (int cc = 0; cc < 2; ++cc) {
            async16(Bbase[cc] + kt * 32, &Bs[ldsB[cc]]);
        }
        __syncthreads();

        bf16x8 af[4], bf[4];
        #pragma unroll
        for (int i = 0; i < 4; ++i) {
            int row = wm * 64 + i * 16 + l16;
            int s0  = (quad * 2) ^ sxor;           // swizzled unit of k-lo half
            f32x4 lo = *(const f32x4*)&As[row * 32 + s0 * 4];
            f32x4 hi = *(const f32x4*)&As[row * 32 + (s0 ^ 1) * 4];
            af[i] = cvt8(lo, hi);
            bf[i] = *(const bf16x8*)&Bs[(wn * 64 + i * 16 + l16) * 32 + quad * 8];
        }
        #pragma unroll
        for (int mi = 0; mi < 4; ++mi)
            #pragma unroll
            for (int ni = 0; ni < 4; ++ni)
                acc[mi][ni] = __builtin_amdgcn_mfma_f32_16x16x32_bf16(
                    af[mi], bf[ni], acc[mi][ni], 0, 0, 0);
        __syncthreads();
    }

    // ---- epilogue: + bias*Berr, ReLU, store fp32 ----
    float mb[4];
    #pragma unroll
    for (int ni = 0; ni < 4; ++ni) {
        int f = nt * 128 + wn * 64 + ni * 16 + l16;
        mb[ni] = bias[f] * Berr[b * F_ + f];
    }
    #pragma unroll
    for (int mi = 0; mi < 4; ++mi) {
        #pragma unroll
        for (int rr = 0; rr < 4; ++rr) {
            int m = pm0 + wm * 64 + mi * 16 + quad * 4 + rr;
            float* orow = Out + ((size_t)b * M_ + m) * F_ + nt * 128 + wn * 64;
            #pragma unroll
            for (int ni = 0; ni < 4; ++ni) {
                float v = acc[mi][ni][rr] + mb[ni];
                orow[ni * 16 + l16] = fmaxf(v, 0.0f);
            }
        }
    }
}

// ---------------------------------------------------------------------------
// Zero-workspace fallback: direct conv, block=(b,h), 256 threads = F.
// Slow (~1ms) but correct; only used if ws_size < 19MB.
// ---------------------------------------------------------------------------
__global__ __launch_bounds__(256)
void fallback_kernel(const float* __restrict__ X, const float* __restrict__ W,
                     const float* __restrict__ bias, const float* __restrict__ Werr,
                     const float* __restrict__ Berr, float* __restrict__ Out) {
    __shared__ float Xs[3 * 66 * 128];
    int bid = blockIdx.x;
    int b = bid >> 6;
    int h = bid & 63;
    int t = threadIdx.x;
    int f = t;

    for (int e = t; e < 3 * 66 * 128; e += 256) {
        int kh  = e / (66 * 128);
        int rem = e - kh * 66 * 128;
        int w66 = rem >> 7;
        int c   = rem & 127;
        int hh = h + kh - 1, ww = w66 - 1;
        float v = 0.f;
        if (hh >= 0 && hh < 64 && ww >= 0 && ww < 64)
            v = X[(((size_t)b * 64 + hh) * 64 + ww) * 128 + c];
        Xs[e] = v;
    }
    __syncthreads();

    float acc[64];
    #pragma unroll
    for (int w = 0; w < 64; ++w) acc[w] = 0.f;

    for (int kk = 0; kk < 9; ++kk) {
        int kh = (kk * 11) >> 5;
        int kw = kk - kh * 3;
        for (int c = 0; c < 128; ++c) {
            size_t wi = ((size_t)kk * 128 + c) * 256 + f;
            float wvv = W[wi] * Werr[(size_t)b * (K_ * F_) + wi];
            const float* xr = &Xs[(kh * 66 + kw) * 128 + c];
            #pragma unroll
            for (int w = 0; w < 64; ++w)
                acc[w] = fmaf(xr[w * 128], wvv, acc[w]);
        }
    }
    float mb = bias[f] * Berr[b * 256 + f];
    for (int w = 0; w < 64; ++w)
        Out[(((size_t)b * 64 + h) * 64 + w) * 256 + f] = fmaxf(acc[w] + mb, 0.f);
}

// ---------------------------------------------------------------------------
extern "C" void kernel_launch(void* const* d_in, const int* in_sizes, int n_in,
                              void* d_out, int out_size, void* d_ws, size_t ws_size,
                              hipStream_t stream) {
    const float* X    = (const float*)d_in[0];
    const float* W    = (const float*)d_in[1];
    const float* bias = (const float*)d_in[2];
    const float* Werr = (const float*)d_in[3];
    const float* Berr = (const float*)d_in[4];
    float* Out = (float*)d_out;

    if (ws_size >= WBT_BYTES + 256) {
        unsigned short* WbT  = (unsigned short*)d_ws;
        unsigned int*   zpg  = (unsigned int*)((char*)d_ws + ZPAGE_OFF);
        wbt_kernel<<<B_ * 36 * 4, 256, 0, stream>>>(W, Werr, WbT, zpg);
        gemm_kernel<<<B_ * 32 * 2, 256, 0, stream>>>(X, WbT, (const float*)zpg,
                                                     bias, Berr, Out);
    } else {
        fallback_kernel<<<B_ * 64, 256, 0, stream>>>(X, W, bias, Werr, Berr, Out);
    }
}

// Round 3
// 355.928 us; speedup vs baseline: 1.0211x; 1.0211x over previous
//
#include <hip/hip_runtime.h>

// Problem constants
#define B_   32
#define H_   64
#define W_   64
#define CIN  128
#define F_   256
#define K_   1152          // 3*3*128
#define M_   4096          // H*W per batch

#define WBT_BYTES ((size_t)B_ * F_ * K_ * 2)   // 18,874,368
#define ZPAGE_OFF WBT_BYTES                    // 256B zero page after WbT

typedef __attribute__((ext_vector_type(8))) short bf16x8;
typedef __attribute__((ext_vector_type(4))) float f32x4;

// pack two floats -> two bf16 (round-to-nearest) in one v_perm
__device__ __forceinline__ unsigned pkbf(float a, float b) {
    unsigned ua = __builtin_bit_cast(unsigned, a) + 0x8000u;
    unsigned ub = __builtin_bit_cast(unsigned, b) + 0x8000u;
    return __builtin_amdgcn_perm(ub, ua, 0x07060302u);
}

__device__ __forceinline__ void async16(const void* g, void* l) {
    __builtin_amdgcn_global_load_lds(
        (const __attribute__((address_space(1))) unsigned int*)g,
        (__attribute__((address_space(3))) unsigned int*)l, 16, 0, 0);
}

// ---------------------------------------------------------------------------
// Kernel B: WbT[b][f][k] = bf16( W[k][f] * Werr[b][k][f] ), vectorized.
// tile 32k x 64f per block; float4 global loads; b128 global stores.
// grid = 32 * 36 * 4 = 4608 blocks, 256 threads.
// ---------------------------------------------------------------------------
__global__ void wbt_kernel(const float* __restrict__ W,
                           const float* __restrict__ Werr,
                           unsigned short* __restrict__ WbT,
                           unsigned int* __restrict__ zpage) {
    __shared__ float tile[32 * 68];   // stride 68: float4-aligned, low conflicts
    int bid = blockIdx.x;
    int ft   = bid & 3;
    int rest = bid >> 2;
    int kt   = rest % 36;
    int b    = rest / 36;
    int k0 = kt * 32;
    int f0 = ft * 64;
    int t  = threadIdx.x;

    if (bid == 0 && t < 64) zpage[t] = 0u;   // 256B zero page, every call

    #pragma unroll
    for (int i = 0; i < 2; ++i) {
        int c   = i * 256 + t;        // 0..511
        int kl  = c >> 4;             // 0..31
        int fl4 = c & 15;             // f offset = fl4*4
        size_t src = (size_t)(k0 + kl) * F_ + f0 + fl4 * 4;
        f32x4 w4 = *(const f32x4*)&W[src];
        f32x4 e4 = *(const f32x4*)&Werr[(size_t)b * (K_ * F_) + src];
        f32x4 v  = w4 * e4;
        *(f32x4*)&tile[kl * 68 + fl4 * 4] = v;
    }
    __syncthreads();
    {
        int c  = t;                   // 256 chunks of 8k x 1f
        int fl = c >> 2;              // 0..63
        int ku = c & 3;               // k unit of 8
        unsigned pk[4];
        #pragma unroll
        for (int j2 = 0; j2 < 4; ++j2) {
            float x0 = tile[(ku * 8 + j2 * 2 + 0) * 68 + fl];
            float x1 = tile[(ku * 8 + j2 * 2 + 1) * 68 + fl];
            pk[j2] = pkbf(x0, x1);
        }
        size_t dst = ((size_t)(b * F_ + f0 + fl)) * K_ + k0 + ku * 8;
        *(uint4*)&WbT[dst] = make_uint4(pk[0], pk[1], pk[2], pk[3]);
    }
}

// ---------------------------------------------------------------------------
// Kernel C: implicit-im2col GEMM.
// A: fp32 X -> regs -> cvt bf16 (once per element) -> ds_write; one-step
//    register prefetch issued after the staging barrier.
// B: bf16 WbT via global_load_lds w16.
// block = 256 thr (4 waves), tile 128(M) x 128(N), BK=32, 36 K-steps.
// grid = 2048; XCD-swizzled so the 32 mt-blocks of one (b,nt) group share
// an XCD (WbT slice 294KB -> L2-resident).
// ---------------------------------------------------------------------------
__global__ __launch_bounds__(256, 2)
void gemm_kernel(const float* __restrict__ X,
                 const unsigned short* __restrict__ WbT,
                 const float* __restrict__ zpage,
                 const float* __restrict__ bias,
                 const float* __restrict__ Berr,
                 float* __restrict__ Out) {
    __shared__ unsigned short As[128 * 32];   // bf16, 8KB, rows of 64B
    __shared__ unsigned short Bs[128 * 32];   // bf16, 8KB, rows of 64B

    int bid = blockIdx.x;
    // XCD swizzle: g = (bid&7) | ((bid>>8)<<3); mt = (bid>>3)&31
    int g   = (bid & 7) | ((bid >> 8) << 3);   // 0..63
    int mt  = (bid >> 3) & 31;
    int b   = g >> 1;
    int nt  = g & 1;
    int pm0 = mt * 128;

    int t    = threadIdx.x;
    int lane = t & 63;
    int wv   = t >> 6;
    int wm   = wv >> 1;
    int wn   = wv & 1;
    int l16  = lane & 15;
    int quad = lane >> 4;

    // ---- A staging state: one half-row (16 channels) per thread ----
    int ml   = t >> 1;              // 0..127
    int half = t & 1;
    int m    = pm0 + ml;
    int hb   = m >> 6;              // 0..63
    int wwv  = m & 63;
    const float* Abase = X + (((size_t)b * 64 + hb - 1) * 64 + (wwv - 1)) * 128
                           + half * 16;
    unsigned vm = 0;
    #pragma unroll
    for (int khw = 0; khw < 9; ++khw) {
        int kh = (khw * 11) >> 5;
        int kw = khw - kh * 3;
        bool ok = ((unsigned)(hb + kh - 1) < 64u) && ((unsigned)(wwv + kw - 1) < 64u);
        vm |= (unsigned)ok << khw;
    }
    int ldsA = ml * 32 + half * 16;  // short index

    // ---- B staging state: 2 async16 chunks per thread ----
    const unsigned short* wb = WbT + ((size_t)(b * F_ + nt * 128)) * K_;
    const unsigned short* Bbase[2];
    int ldsB[2];
    #pragma unroll
    for (int cc = 0; cc < 2; ++cc) {
        int c   = t + cc * 256;
        int nl  = c >> 2;
        int off = c & 3;
        Bbase[cc] = wb + (size_t)nl * K_ + off * 8;
        ldsB[cc]  = c * 8;
    }

    f32x4 acc[4][4];
    #pragma unroll
    for (int mi = 0; mi < 4; ++mi)
        #pragma unroll
        for (int ni = 0; ni < 4; ++ni)
            acc[mi][ni] = (f32x4){0.f, 0.f, 0.f, 0.f};

    // prefetch regs for A (16 fp32)
    f32x4 pr0, pr1, pr2, pr3;
    {
        const float* p = (vm & 1) ? Abase : zpage;
        pr0 = *(const f32x4*)(p);
        pr1 = *(const f32x4*)(p + 4);
        pr2 = *(const f32x4*)(p + 8);
        pr3 = *(const f32x4*)(p + 12);
    }

    for (int kt = 0; kt < 36; ++kt) {
        // cvt prefetched A (registers only)
        uint4 lo, hi;
        lo.x = pkbf(pr0[0], pr0[1]);  lo.y = pkbf(pr0[2], pr0[3]);
        lo.z = pkbf(pr1[0], pr1[1]);  lo.w = pkbf(pr1[2], pr1[3]);
        hi.x = pkbf(pr2[0], pr2[1]);  hi.y = pkbf(pr2[2], pr2[3]);
        hi.z = pkbf(pr3[0], pr3[1]);  hi.w = pkbf(pr3[2], pr3[3]);

        if (kt) __syncthreads();           // LDS consumers of kt-1 done
        *(uint4*)&As[ldsA]     = lo;
        *(uint4*)&As[ldsA + 8] = hi;
        #pragma unroll
        for (int cc = 0; cc < 2; ++cc)
            async16(Bbase[cc] + kt * 32, &Bs[ldsB[cc]]);
        __syncthreads();                   // staging visible (vmcnt drained)

        // issue next A loads; they drain at next iteration's first barrier
        if (kt < 35) {
            int ktn  = kt + 1;
            int khw  = ktn >> 2;
            int kh   = (khw * 11) >> 5;
            int kw   = khw - kh * 3;
            int koff = kh * 8192 + kw * 128 + ((ktn & 3) << 5);
            const float* p = ((vm >> khw) & 1) ? Abase + koff : zpage;
            pr0 = *(const f32x4*)(p);
            pr1 = *(const f32x4*)(p + 4);
            pr2 = *(const f32x4*)(p + 8);
            pr3 = *(const f32x4*)(p + 12);
        }

        bf16x8 af[4], bf[4];
        #pragma unroll
        for (int i = 0; i < 4; ++i) {
            af[i] = *(const bf16x8*)&As[(wm * 64 + i * 16 + l16) * 32 + quad * 8];
            bf[i] = *(const bf16x8*)&Bs[(wn * 64 + i * 16 + l16) * 32 + quad * 8];
        }
        #pragma unroll
        for (int mi = 0; mi < 4; ++mi)
            #pragma unroll
            for (int ni = 0; ni < 4; ++ni)
                acc[mi][ni] = __builtin_amdgcn_mfma_f32_16x16x32_bf16(
                    af[mi], bf[ni], acc[mi][ni], 0, 0, 0);
    }

    // ---- epilogue: + bias*Berr, ReLU, store fp32 ----
    float mb[4];
    #pragma unroll
    for (int ni = 0; ni < 4; ++ni) {
        int f = nt * 128 + wn * 64 + ni * 16 + l16;
        mb[ni] = bias[f] * Berr[b * F_ + f];
    }
    #pragma unroll
    for (int mi = 0; mi < 4; ++mi) {
        #pragma unroll
        for (int rr = 0; rr < 4; ++rr) {
            int mm = pm0 + wm * 64 + mi * 16 + quad * 4 + rr;
            float* orow = Out + ((size_t)b * M_ + mm) * F_ + nt * 128 + wn * 64;
            #pragma unroll
            for (int ni = 0; ni < 4; ++ni) {
                float v = acc[mi][ni][rr] + mb[ni];
                orow[ni * 16 + l16] = fmaxf(v, 0.0f);
            }
        }
    }
}

// ---------------------------------------------------------------------------
// Zero-workspace fallback: direct conv (slow but correct), ws < 19MB only.
// ---------------------------------------------------------------------------
__global__ __launch_bounds__(256)
void fallback_kernel(const float* __restrict__ X, const float* __restrict__ W,
                     const float* __restrict__ bias, const float* __restrict__ Werr,
                     const float* __restrict__ Berr, float* __restrict__ Out) {
    __shared__ float Xs[3 * 66 * 128];
    int bid = blockIdx.x;
    int b = bid >> 6;
    int h = bid & 63;
    int t = threadIdx.x;
    int f = t;

    for (int e = t; e < 3 * 66 * 128; e += 256) {
        int kh  = e / (66 * 128);
        int rem = e - kh * 66 * 128;
        int w66 = rem >> 7;
        int c   = rem & 127;
        int hh = h + kh - 1, ww = w66 - 1;
        float v = 0.f;
        if (hh >= 0 && hh < 64 && ww >= 0 && ww < 64)
            v = X[(((size_t)b * 64 + hh) * 64 + ww) * 128 + c];
        Xs[e] = v;
    }
    __syncthreads();

    float acc[64];
    #pragma unroll
    for (int w = 0; w < 64; ++w) acc[w] = 0.f;

    for (int kk = 0; kk < 9; ++kk) {
        int kh = (kk * 11) >> 5;
        int kw = kk - kh * 3;
        for (int c = 0; c < 128; ++c) {
            size_t wi = ((size_t)kk * 128 + c) * 256 + f;
            float wvv = W[wi] * Werr[(size_t)b * (K_ * F_) + wi];
            const float* xr = &Xs[(kh * 66 + kw) * 128 + c];
            #pragma unroll
            for (int w = 0; w < 64; ++w)
                acc[w] = fmaf(xr[w * 128], wvv, acc[w]);
        }
    }
    float mb = bias[f] * Berr[b * 256 + f];
    for (int w = 0; w < 64; ++w)
        Out[(((size_t)b * 64 + h) * 64 + w) * 256 + f] = fmaxf(acc[w] + mb, 0.f);
}

// ---------------------------------------------------------------------------
extern "C" void kernel_launch(void* const* d_in, const int* in_sizes, int n_in,
                              void* d_out, int out_size, void* d_ws, size_t ws_size,
                              hipStream_t stream) {
    const float* X    = (const float*)d_in[0];
    const float* W    = (const float*)d_in[1];
    const float* bias = (const float*)d_in[2];
    const float* Werr = (const float*)d_in[3];
    const float* Berr = (const float*)d_in[4];
    float* Out = (float*)d_out;

    if (ws_size >= WBT_BYTES + 256) {
        unsigned short* WbT  = (unsigned short*)d_ws;
        unsigned int*   zpg  = (unsigned int*)((char*)d_ws + ZPAGE_OFF);
        wbt_kernel<<<B_ * 36 * 4, 256, 0, stream>>>(W, Werr, WbT, zpg);
        gemm_kernel<<<B_ * 32 * 2, 256, 0, stream>>>(X, WbT, (const float*)zpg,
                                                     bias, Berr, Out);
    } else {
        fallback_kernel<<<B_ * 64, 256, 0, stream>>>(X, W, bias, Werr, Berr, Out);
    }
}